// Round 7
// baseline (239.101 us; speedup 1.0000x reference)
//
#include <hip/hip_runtime.h>

typedef short short8 __attribute__((ext_vector_type(8)));
typedef float f32x4 __attribute__((ext_vector_type(4)));

#define B_ROWS 32768
#define DIN 784
#define D_DIM 256
#define T_TILES 16
#define C_DIM 64
#define BM 64
#define NCHUNK 25   // ceil(784/32)

// ---- ws layout (bytes) ----
#define WPT_OFF    0u          // bf16 [25][256][32]  = 409600
#define WCT_OFF    409600u     // bf16 [16][64][256]  = 524288
#define WS_OFF     933888u     // f64  [800][16]      = 102400 (rows 784..799 zeroed)
#define BS_OFF     1036288u    // f64  [16]
#define H_OFF      1036416u    // bf16 [32768][256]   = 16777216
#define BUCKET_OFF 17813632u   // i32  [16][32768]    = 2097152
#define CNT_OFF    19910784u   // i32  [16]

static __device__ inline unsigned short f2bf(float f) {
    unsigned u = __builtin_bit_cast(unsigned, f);
    u += 0x7fffu + ((u >> 16) & 1u);          // RNE
    return (unsigned short)(u >> 16);
}
static __device__ inline double qtern(float s) {
    double v = (double)s;
    return (v > 0.3) ? 1.0 : ((v < -0.3) ? -1.0 : 0.0);
}

// ================= prep: WpT chunks (bf16), WcT (bf16), Ws/bs (f64), cnt=0 ==
__global__ __launch_bounds__(256)
void prep_kernel(const float* __restrict__ Wp, const float* __restrict__ bp,
                 const float* __restrict__ sigs_raw, const float* __restrict__ Wc,
                 char* __restrict__ ws) {
    __shared__ __align__(16) char u2[34816];
    const int bid = blockIdx.x, tid = threadIdx.x;
    unsigned short* wpt = (unsigned short*)(ws + WPT_OFF);
    unsigned short* wct = (unsigned short*)(ws + WCT_OFF);
    double* Wsd = (double*)(ws + WS_OFF);
    double* bsd = (double*)(ws + BS_OFF);

    if (bid < 25) {
        // WpT chunk transpose: Wp[k0..k0+32)[256] -> wpt[chunk][col][k&31], coalesced out
        unsigned short (*lt)[40] = (unsigned short (*)[40])u2;    // [256][40]
        const int k0 = bid * 32;
        #pragma unroll
        for (int p = 0; p < 8; ++p) {
            const int k = p * 4 + (tid >> 6);
            const int c = (tid & 63) * 4;
            float4 v = make_float4(0.f, 0.f, 0.f, 0.f);
            if (k0 + k < DIN) v = *(const float4*)&Wp[(size_t)(k0 + k) * D_DIM + c];
            lt[c + 0][k] = f2bf(v.x); lt[c + 1][k] = f2bf(v.y);
            lt[c + 2][k] = f2bf(v.z); lt[c + 3][k] = f2bf(v.w);
        }
        __syncthreads();
        const float4* src = (const float4*)&lt[tid][0];
        float4* dst = (float4*)(wpt + bid * 8192 + tid * 32);
        dst[0] = src[0]; dst[1] = src[1]; dst[2] = src[2]; dst[3] = src[3];
    } else if (bid < 123) {
        // Ws[k0..k0+8)[16] in f64
        float* sigq = (float*)u2;               // [16][256]
        float* wp8  = (float*)(u2 + 16384);     // [8][256]
        const int k0 = (bid - 25) * 8;
        #pragma unroll
        for (int i = 0; i < 16; ++i) {
            const int idx = i * 256 + tid;
            sigq[idx] = (float)qtern(sigs_raw[idx]);
        }
        #pragma unroll
        for (int i = 0; i < 8; ++i)
            wp8[i * 256 + tid] = Wp[(size_t)(k0 + i) * D_DIM + tid];
        __syncthreads();
        const int kk = tid >> 5, t = (tid >> 1) & 15, half = tid & 1;
        double s = 0.0;
        const float* wr = &wp8[kk * 256 + half * 128];
        const float* sq = &sigq[t * 256 + half * 128];
        for (int d = 0; d < 128; ++d) s += (double)wr[d] * (double)sq[d];
        s += __shfl_xor(s, 1);
        if (half == 0) Wsd[(k0 + kk) * 16 + t] = s;
    } else if (bid < 139) {
        // WcT[t][c][d] bf16, coalesced out
        unsigned short (*lc)[264] = (unsigned short (*)[264])u2;  // [64][264]
        const int t = bid - 123;
        #pragma unroll
        for (int j = 0; j < 16; ++j) {
            const int f4 = j * 256 + tid;
            const int d  = f4 >> 4;
            const int c4 = (f4 & 15) * 4;
            const float4 v = *(const float4*)&Wc[((size_t)t * D_DIM + d) * C_DIM + c4];
            lc[c4 + 0][d] = f2bf(v.x); lc[c4 + 1][d] = f2bf(v.y);
            lc[c4 + 2][d] = f2bf(v.z); lc[c4 + 3][d] = f2bf(v.w);
        }
        __syncthreads();
        const int c = tid >> 2, d0 = (tid & 3) * 64;
        const float4* src = (const float4*)&lc[c][d0];
        float4* dst = (float4*)(wct + t * 16384 + c * 256 + d0);
        #pragma unroll
        for (int i = 0; i < 8; ++i) dst[i] = src[i];
    } else {
        // bs[t] = bp @ sig_t ; zero Ws pad rows ; zero cnt
        int* cnt = (int*)(ws + CNT_OFF);
        if (tid < 16) cnt[tid] = 0;
        Wsd[12544 + tid] = 0.0;     // rows 784..799
        const int t = tid >> 4, l = tid & 15;
        double s = 0.0;
        #pragma unroll
        for (int j = 0; j < 16; ++j) {
            const int d = l * 16 + j;
            s += (double)bp[d] * qtern(sigs_raw[t * D_DIM + d]);
        }
        #pragma unroll
        for (int m = 8; m >= 1; m >>= 1) s += __shfl_xor(s, m);
        if (l == 0) bsd[t] = s;
    }
}

// ====== main: h = x@Wp+bp (bf16 MFMA, B-frags from L2) + fused f64 scores ====
__global__ __launch_bounds__(256, 3)
void gemm_score_kernel(const float* __restrict__ x, const float* __restrict__ bp,
                       char* __restrict__ ws, float* __restrict__ out) {
    __shared__ __align__(16) char u[33792];     // Abuf+wss2, later h_s [64][264]
    __shared__ int tidx_s[BM];

    unsigned short* Abuf = (unsigned short*)u;   // [2][64*40] bf16 = 10240 B
    char* wssb = u + 10240;                      // [2][4608] B padded double2 Ws

    const unsigned short* wpt = (const unsigned short*)(ws + WPT_OFF);
    unsigned short* hbf = (unsigned short*)(ws + H_OFF);
    const double* Wsd = (const double*)(ws + WS_OFF);
    const double* bsd = (const double*)(ws + BS_OFF);
    int* bucket = (int*)(ws + BUCKET_OFF);
    int* cnt = (int*)(ws + CNT_OFF);

    const int tid = threadIdx.x;
    const int row0 = blockIdx.x * BM;
    const int wid = tid >> 6, lane = tid & 63;
    const int wr = wid >> 1, wcid = wid & 1;
    const int lrow = lane & 15, kb8 = (lane >> 4) * 8;
    const int ar = tid >> 2, aq = tid & 3, ako = aq * 8;   // A/score row + k-quarter
    const int wtp = tid >> 5, wkk = tid & 31;              // Ws staging: t-pair, k

    f32x4 acc[2][8];
    #pragma unroll
    for (int i = 0; i < 2; ++i)
        #pragma unroll
        for (int j = 0; j < 8; ++j) acc[i][j] = (f32x4){0.f, 0.f, 0.f, 0.f};
    double accd[16];
    #pragma unroll
    for (int t = 0; t < 16; ++t) accd[t] = 0.0;
    float xs8[8];

    const int wsoff = wtp * 576 + wkk * 16 + (wkk >> 3) * 16;   // staging LDS offset
    const char* wrd_base = wssb + aq * 144;                      // score read base

    // ---- prologue: stage chunk 0 (x regs->Abuf[0], Ws->wss2[0]) ----
    {
        const float4* p = (const float4*)&x[(size_t)(row0 + ar) * DIN + ako];
        const float4 a0 = p[0], a1 = p[1];
        xs8[0] = a0.x; xs8[1] = a0.y; xs8[2] = a0.z; xs8[3] = a0.w;
        xs8[4] = a1.x; xs8[5] = a1.y; xs8[6] = a1.z; xs8[7] = a1.w;
        unsigned short tmp[8];
        #pragma unroll
        for (int i = 0; i < 8; ++i) tmp[i] = f2bf(xs8[i]);
        *(short8*)(Abuf + ar * 40 + ako) = *(short8*)tmp;
        const double2 wv = *(const double2*)&Wsd[wkk * 16 + wtp * 2];
        *(double2*)(wssb + wsoff) = wv;
    }
    __syncthreads();

    for (int c = 0; c < NCHUNK; ++c) {
        const int cur = c & 1;
        const bool more = (c + 1 < NCHUNK);

        // ---- B-fragments for chunk c straight from L2-resident wpt ----
        short8 bfr[8];
        #pragma unroll
        for (int cf = 0; cf < 8; ++cf)
            bfr[cf] = *(const short8*)(wpt + c * 8192 + (wcid * 128 + cf * 16 + lrow) * 32 + kb8);

        // ---- next-chunk x + Ws global loads ----
        float4 va0, va1; double2 wv;
        if (more) {
            const int kbase = (c + 1) * 32 + ako;
            if (kbase < DIN) {
                const float4* p = (const float4*)&x[(size_t)(row0 + ar) * DIN + kbase];
                va0 = p[0]; va1 = p[1];
            } else {
                va0 = make_float4(0, 0, 0, 0); va1 = make_float4(0, 0, 0, 0);
            }
            wv = *(const double2*)&Wsd[((c + 1) * 32 + wkk) * 16 + wtp * 2];
        }

        // ---- fused f64 score FMAs (LDS wss2[cur] double2, bank-disjoint) ----
        {
            const char* wb = wrd_base + cur * 4608;
            #pragma unroll
            for (int i = 0; i < 8; ++i) {
                const double xd = (double)xs8[i];
                #pragma unroll
                for (int tp = 0; tp < 8; ++tp) {
                    const double2 w2 = *(const double2*)(wb + tp * 576 + i * 16);
                    accd[2 * tp]     += xd * w2.x;
                    accd[2 * tp + 1] += xd * w2.y;
                }
            }
        }

        // ---- MFMA chunk c (A from LDS, B from regs) ----
        {
            const unsigned short* Ab = Abuf + cur * 2560;
            const short8 af0 = *(const short8*)(Ab + (wr * 32 + lrow) * 40 + kb8);
            const short8 af1 = *(const short8*)(Ab + (wr * 32 + 16 + lrow) * 40 + kb8);
            #pragma unroll
            for (int cf = 0; cf < 8; ++cf) {
                acc[0][cf] = __builtin_amdgcn_mfma_f32_16x16x32_bf16(af0, bfr[cf], acc[0][cf], 0, 0, 0);
                acc[1][cf] = __builtin_amdgcn_mfma_f32_16x16x32_bf16(af1, bfr[cf], acc[1][cf], 0, 0, 0);
            }
        }

        // ---- stage next chunk into the other buffers ----
        if (more) {
            xs8[0] = va0.x; xs8[1] = va0.y; xs8[2] = va0.z; xs8[3] = va0.w;
            xs8[4] = va1.x; xs8[5] = va1.y; xs8[6] = va1.z; xs8[7] = va1.w;
            unsigned short tmp[8];
            #pragma unroll
            for (int i = 0; i < 8; ++i) tmp[i] = f2bf(xs8[i]);
            *(short8*)(Abuf + (cur ^ 1) * 2560 + ar * 40 + ako) = *(short8*)tmp;
            *(double2*)(wssb + (cur ^ 1) * 4608 + wsoff) = wv;
        }
        __syncthreads();
    }

    // ---- epilogue: h = acc + bp -> LDS (then coalesced global write) ----
    unsigned short* h_s = (unsigned short*)u;    // [64][264], aliases A/ws bufs
    #pragma unroll
    for (int cf = 0; cf < 8; ++cf) {
        const int gc = wcid * 128 + cf * 16 + lrow;
        const float bpv = bp[gc];
        #pragma unroll
        for (int rf = 0; rf < 2; ++rf) {
            const int lr = wr * 32 + rf * 16 + (lane >> 4) * 4;
            #pragma unroll
            for (int r = 0; r < 4; ++r)
                h_s[(lr + r) * 264 + gc] = f2bf(acc[rf][cf][r] + bpv);
        }
    }

    // ---- score reduce (4 k-quarters per row) + argmax ----
    #pragma unroll
    for (int t = 0; t < 16; ++t) {
        accd[t] += __shfl_xor(accd[t], 1);
        accd[t] += __shfl_xor(accd[t], 2);
    }
    if (aq == 0) {
        double best = -1.0e300; int bi = 0;
        #pragma unroll
        for (int t = 0; t < 16; ++t) {
            const double v = accd[t] + bsd[t];
            if (v > best) { best = v; bi = t; }
        }
        tidx_s[ar] = bi;
        out[(size_t)B_ROWS * C_DIM + row0 + ar] = (float)bi;
    }
    __syncthreads();

    // ---- coalesced h write: 64 shorts (8x float4) per thread ----
    {
        const int r = tid >> 2, q = tid & 3;
        const float4* src = (const float4*)(h_s + r * 264 + q * 64);
        float4 v[8];
        #pragma unroll
        for (int i = 0; i < 8; ++i) v[i] = src[i];
        float4* dst = (float4*)(hbf + (size_t)(row0 + r) * D_DIM + q * 64);
        #pragma unroll
        for (int i = 0; i < 8; ++i) dst[i] = v[i];
    }

    // ---- global bucketing ----
    if (tid < T_TILES) {
        int c = 0;
        for (int r = 0; r < BM; ++r) c += (tidx_s[r] == tid);
        int pos = atomicAdd(&cnt[tid], c);
        for (int r = 0; r < BM; ++r)
            if (tidx_s[r] == tid) bucket[tid * B_ROWS + (pos++)] = row0 + r;
    }
}

// ====== L: per-tile logits = h[rows] @ Wc[t] + bc[t] via MFMA (64-row blocks)
#define LBM 64
__global__ __launch_bounds__(256)
void logits_kernel(const float* __restrict__ bc, const char* __restrict__ ws,
                   float* __restrict__ out) {
    __shared__ __align__(16) unsigned short As[LBM * 136];
    __shared__ __align__(16) unsigned short Bs[64 * 136];
    __shared__ int rows_s[LBM];

    const int tid = threadIdx.x;
    const int t = blockIdx.x >> 9;
    const int c0 = (blockIdx.x & 511) * LBM;
    const int* cnt = (const int*)(ws + CNT_OFF);
    const int cntv = cnt[t];
    if (c0 >= cntv) return;

    const int* bucket = (const int*)(ws + BUCKET_OFF);
    const unsigned short* hbf = (const unsigned short*)(ws + H_OFF);
    const unsigned short* wct = (const unsigned short*)(ws + WCT_OFF);

    if (tid < LBM) {
        int i = c0 + tid; if (i >= cntv) i = cntv - 1;
        rows_s[tid] = bucket[t * B_ROWS + i];
    }
    __syncthreads();

    const int wid = tid >> 6, lane = tid & 63;
    const int wr = wid >> 1, wcid = wid & 1;
    const int lrow = lane & 15, kb8 = (lane >> 4) * 8;
    const int sr = tid >> 2, sq = tid & 3;     // staging: row/col, 32-short quarter

    f32x4 acc[2][2];
    #pragma unroll
    for (int i = 0; i < 2; ++i) { acc[i][0] = (f32x4){0,0,0,0}; acc[i][1] = (f32x4){0,0,0,0}; }

    #pragma unroll
    for (int ch = 0; ch < 2; ++ch) {
        const int k0 = ch * 128;
        if (ch) __syncthreads();
        {   // A: 64 rows x 128 k-shorts; 4 threads/row x 32 shorts = 4x float4
            const float4* p = (const float4*)(hbf + (size_t)rows_s[sr] * D_DIM + k0 + sq * 32);
            float4 v[4];
            #pragma unroll
            for (int i = 0; i < 4; ++i) v[i] = p[i];
            float4* d = (float4*)(As + sr * 136 + sq * 32);
            #pragma unroll
            for (int i = 0; i < 4; ++i) d[i] = v[i];
        }
        {   // B: 64 cols x 128 k-shorts; 4 threads/col x 32 shorts = 4x float4
            const float4* p = (const float4*)(wct + (size_t)t * 16384 + sr * 256 + k0 + sq * 32);
            float4 v[4];
            #pragma unroll
            for (int i = 0; i < 4; ++i) v[i] = p[i];
            float4* d = (float4*)(Bs + sr * 136 + sq * 32);
            #pragma unroll
            for (int i = 0; i < 4; ++i) d[i] = v[i];
        }
        __syncthreads();
        #pragma unroll
        for (int ks = 0; ks < 4; ++ks) {
            const int kb = ks * 32 + kb8;
            const short8 bf0 = *(const short8*)(Bs + (wcid * 32 + lrow) * 136 + kb);
            const short8 bf1 = *(const short8*)(Bs + (wcid * 32 + 16 + lrow) * 136 + kb);
            #pragma unroll
            for (int rf = 0; rf < 2; ++rf) {
                const short8 af = *(const short8*)(As + (wr * 32 + rf * 16 + lrow) * 136 + kb);
                acc[rf][0] = __builtin_amdgcn_mfma_f32_16x16x32_bf16(af, bf0, acc[rf][0], 0, 0, 0);
                acc[rf][1] = __builtin_amdgcn_mfma_f32_16x16x32_bf16(af, bf1, acc[rf][1], 0, 0, 0);
            }
        }
    }

    #pragma unroll
    for (int cf = 0; cf < 2; ++cf) {
        const int col = wcid * 32 + cf * 16 + lrow;
        const float bcv = bc[t * C_DIM + col];
        #pragma unroll
        for (int rf = 0; rf < 2; ++rf) {
            const int lr = wr * 32 + rf * 16 + (lane >> 4) * 4;
            #pragma unroll
            for (int r = 0; r < 4; ++r)
                out[(size_t)rows_s[lr + r] * C_DIM + col] = acc[rf][cf][r] + bcv;
        }
    }
}

extern "C" void kernel_launch(void* const* d_in, const int* in_sizes, int n_in,
                              void* d_out, int out_size, void* d_ws, size_t ws_size,
                              hipStream_t stream) {
    const float* x    = (const float*)d_in[0];
    const float* Wp   = (const float*)d_in[1];
    const float* bp   = (const float*)d_in[2];
    const float* sigs = (const float*)d_in[3];
    const float* Wc   = (const float*)d_in[4];
    const float* bc   = (const float*)d_in[5];
    float* out = (float*)d_out;
    char* ws = (char*)d_ws;

    prep_kernel<<<dim3(140), dim3(256), 0, stream>>>(Wp, bp, sigs, Wc, ws);
    gemm_score_kernel<<<dim3(B_ROWS / BM), dim3(256), 0, stream>>>(x, bp, ws, out);
    logits_kernel<<<dim3(16 * 512), dim3(256), 0, stream>>>(bc, ws, out);
}